// Round 2
// baseline (298.500 us; speedup 1.0000x reference)
//
#include <hip/hip_runtime.h>

#define B_TOTAL 32768
#define NF 200
#define D_IN 5
#define NH 15
#define NOUT 30
#define RECS 216          // per-f record: [bc 30][w3 30][Wc 150 (i-major)][pad 6] -> 864 B, 16B aligned

// ---------------- Precompute: fold W1*W2, b1*W2+b2, copy w3 into aligned per-f records ----------------
__global__ __launch_bounds__(256) void precompute_kernel(
    const float* __restrict__ W1, const float* __restrict__ b1,
    const float* __restrict__ W2, const float* __restrict__ b2,
    const float* __restrict__ W3, float* __restrict__ rec)
{
    const int f = blockIdx.x;
    const int t = threadIdx.x;
    float* r = rec + f * RECS;
    if (t < NOUT) {
        const int o = t;
        float s = b2[f * NOUT + o];
        #pragma unroll
        for (int h = 0; h < NH; ++h)
            s = fmaf(b1[f * NH + h], W2[(f * NH + h) * NOUT + o], s);
        r[o] = s;                                  // bc
    } else if (t < 2 * NOUT) {
        const int o = t - NOUT;
        r[NOUT + o] = W3[f * NOUT + o];            // w3 copy
    } else if (t < 2 * NOUT + D_IN * NOUT) {
        const int j = t - 2 * NOUT;
        const int i = j / NOUT;
        const int o = j - i * NOUT;
        float s = 0.f;
        #pragma unroll
        for (int h = 0; h < NH; ++h)
            s = fmaf(W1[(f * D_IN + i) * NH + h], W2[(f * NH + h) * NOUT + o], s);
        r[2 * NOUT + i * NOUT + o] = s;            // Wc, i-major
    }
}

// ---------------- Main fused kernel: no LDS for y, weights via s_load ----------------
#define BTILE 64          // batch rows per block (one per lane)
#define NSUB 10           // waves per block; each wave owns 20 f's
#define FSUB 20           // f's per wave: 20 f * 5 = 100 floats = 400 B (16B aligned per sub)
#define NCHUNK 5          // 20 f in chunks of 4 f (20 floats = 5 float4)

__global__ __launch_bounds__(640, 5) void mlp_kernel(
    const float* __restrict__ y, const float* __restrict__ rec,
    const float* __restrict__ b3, float* __restrict__ out)
{
    __shared__ float red[BTILE * NSUB];

    const int tid  = threadIdx.x;
    const int lane = tid & 63;
    const int sub  = tid >> 6;                             // 0..9
    const int sub_u = __builtin_amdgcn_readfirstlane(sub); // provably wave-uniform
    const int b0   = blockIdx.x * BTILE;
    const int b    = b0 + lane;

    const float* yp   = y + (size_t)b * (NF * D_IN) + sub_u * (FSUB * D_IN);
    const float* wrec = rec + sub_u * FSUB * RECS;         // uniform

    const float4* yq = (const float4*)yp;
    float4 c0 = yq[0], c1 = yq[1], c2 = yq[2], c3 = yq[3], c4 = yq[4];

    float acc[4] = {0.f, 0.f, 0.f, 0.f};

    #pragma unroll 1
    for (int cc = 0; cc < NCHUNK; ++cc) {
        // prefetch next chunk (double buffer)
        float4 n0, n1, n2, n3, n4;
        if (cc < NCHUNK - 1) {
            const float4* nq = yq + (cc + 1) * 5;
            n0 = nq[0]; n1 = nq[1]; n2 = nq[2]; n3 = nq[3]; n4 = nq[4];
        } else {
            n0 = c0; n1 = c1; n2 = c2; n3 = c3; n4 = c4;
        }

        float yv[20];
        *(float4*)&yv[0]  = c0;
        *(float4*)&yv[4]  = c1;
        *(float4*)&yv[8]  = c2;
        *(float4*)&yv[12] = c3;
        *(float4*)&yv[16] = c4;

        #pragma unroll
        for (int k = 0; k < 4; ++k) {
            const float* __restrict__ r = wrec + (cc * 4 + k) * RECS;  // uniform -> s_load
            float z[NOUT];
            #pragma unroll
            for (int o = 0; o < NOUT; ++o) z[o] = r[o];                // bc
            #pragma unroll
            for (int i = 0; i < D_IN; ++i) {
                const float yvi = yv[k * 5 + i];
                #pragma unroll
                for (int o = 0; o < NOUT; ++o)
                    z[o] = fmaf(yvi, r[2 * NOUT + i * NOUT + o], z[o]);
            }
            #pragma unroll
            for (int o = 0; o < NOUT; ++o)
                acc[o & 3] = fmaf(fmaxf(z[o], 0.f), r[NOUT + o], acc[o & 3]);
        }

        c0 = n0; c1 = n1; c2 = n2; c3 = n3; c4 = n4;
    }

    red[lane * NSUB + sub] = (acc[0] + acc[1]) + (acc[2] + acc[3]);
    __syncthreads();

    if (tid < BTILE) {
        float s = b3[0];
        #pragma unroll
        for (int k = 0; k < NSUB; ++k) s += red[tid * NSUB + k];
        out[b0 + tid] = s;
    }
}

extern "C" void kernel_launch(void* const* d_in, const int* in_sizes, int n_in,
                              void* d_out, int out_size, void* d_ws, size_t ws_size,
                              hipStream_t stream) {
    const float* y  = (const float*)d_in[0];
    const float* W1 = (const float*)d_in[1];
    const float* b1 = (const float*)d_in[2];
    const float* W2 = (const float*)d_in[3];
    const float* b2 = (const float*)d_in[4];
    const float* W3 = (const float*)d_in[5];
    const float* b3 = (const float*)d_in[6];
    float* out = (float*)d_out;

    float* rec = (float*)d_ws;   // 200 * 216 floats = 172.8 KB

    precompute_kernel<<<NF, 256, 0, stream>>>(W1, b1, W2, b2, W3, rec);
    mlp_kernel<<<B_TOTAL / BTILE, BTILE * NSUB, 0, stream>>>(y, rec, b3, out);
}

// Round 3
// 229.392 us; speedup vs baseline: 1.3013x; 1.3013x over previous
//
#include <hip/hip_runtime.h>

#define B_TOTAL 32768
#define NF 200
#define D_IN 5
#define NH 15
#define NOUT 30
#define RECS 216          // per-f record: [bc 30][w3 30][Wc 150 (i-major)][pad 6] -> 864 B, 8B/16B aligned

typedef float v2f __attribute__((ext_vector_type(2)));
typedef float v4f __attribute__((ext_vector_type(4)));

// ---------------- Precompute: fold W1*W2, b1*W2+b2, copy w3 into aligned per-f records ----------------
__global__ __launch_bounds__(256) void precompute_kernel(
    const float* __restrict__ W1, const float* __restrict__ b1,
    const float* __restrict__ W2, const float* __restrict__ b2,
    const float* __restrict__ W3, float* __restrict__ rec)
{
    const int f = blockIdx.x;
    const int t = threadIdx.x;
    float* r = rec + f * RECS;
    if (t < NOUT) {
        const int o = t;
        float s = b2[f * NOUT + o];
        #pragma unroll
        for (int h = 0; h < NH; ++h)
            s = fmaf(b1[f * NH + h], W2[(f * NH + h) * NOUT + o], s);
        r[o] = s;                                  // bc
    } else if (t < 2 * NOUT) {
        const int o = t - NOUT;
        r[NOUT + o] = W3[f * NOUT + o];            // w3 copy
    } else if (t < 2 * NOUT + D_IN * NOUT) {
        const int j = t - 2 * NOUT;
        const int i = j / NOUT;
        const int o = j - i * NOUT;
        float s = 0.f;
        #pragma unroll
        for (int h = 0; h < NH; ++h)
            s = fmaf(W1[(f * D_IN + i) * NH + h], W2[(f * NH + h) * NOUT + o], s);
        r[2 * NOUT + i * NOUT + o] = s;            // Wc, i-major, o contiguous (pair-friendly)
    }
}

// ---------------- Main fused kernel ----------------
// lane = batch row (direct global float4 y loads, vmcnt stream)
// weights = wave-uniform s_load (lgkmcnt stream) -> disjoint counters, no barriers in hot loop
#define BTILE 64          // batch rows per block (one per lane)
#define NSUB 10           // waves per block; each wave owns FSUB f's
#define FSUB 20           // 20 f * 5 = 100 floats y-slice per lane, float4-aligned per wave
#define NCHUNK 5          // 20 f in chunks of 4 f (20 floats = 5 float4)

__global__ __launch_bounds__(640, 5) void mlp_kernel(
    const float* __restrict__ y, const float* __restrict__ rec,
    const float* __restrict__ b3, float* __restrict__ out)
{
    __shared__ float red[BTILE * NSUB];

    const int tid   = threadIdx.x;
    const int lane  = tid & 63;
    const int sub   = tid >> 6;                             // 0..9
    const int sub_u = __builtin_amdgcn_readfirstlane(sub);  // provably wave-uniform
    const int b0    = blockIdx.x * BTILE;
    const int b     = b0 + lane;

    const v4f* __restrict__ yq =
        (const v4f*)(y + (size_t)b * (NF * D_IN) + sub_u * (FSUB * D_IN));
    const float* __restrict__ wrec = rec + (size_t)sub_u * FSUB * RECS;  // uniform

    v2f acc0 = (v2f)0.0f, acc1 = (v2f)0.0f;

    #pragma unroll 1
    for (int cc = 0; cc < NCHUNK; ++cc) {
        // 20 y floats for this 4-f group, as 5 float4 regs (constant-indexed only; no punning)
        v4f yv[5];
        #pragma unroll
        for (int j = 0; j < 5; ++j) yv[j] = yq[cc * 5 + j];

        #pragma unroll
        for (int k = 0; k < 4; ++k) {
            const float* __restrict__ r  = wrec + (cc * 4 + k) * RECS;  // uniform
            const v2f* __restrict__ rb   = (const v2f*)r;               // bc  pairs [0..15)
            const v2f* __restrict__ rw3  = (const v2f*)(r + NOUT);      // w3  pairs
            const v2f* __restrict__ rw   = (const v2f*)(r + 2 * NOUT);  // Wc  pairs, rw[i*15+p]

            v2f z[15];
            {   // i = 0 folded with bc init
                const int e = k * 5;
                const float y0 = yv[e >> 2][e & 3];
                #pragma unroll
                for (int p = 0; p < 15; ++p) z[p] = rb[p] + y0 * rw[p];
            }
            #pragma unroll
            for (int i = 1; i < D_IN; ++i) {
                const int e = k * 5 + i;
                const float yi = yv[e >> 2][e & 3];
                #pragma unroll
                for (int p = 0; p < 15; ++p) z[p] += yi * rw[i * 15 + p];
            }
            #pragma unroll
            for (int p = 0; p < 15; ++p) {
                v2f zr = __builtin_elementwise_max(z[p], (v2f)0.0f);   // v_pk_max_f32
                if (p & 1) acc1 += zr * rw3[p];
                else       acc0 += zr * rw3[p];
            }
        }
    }

    v2f accs = acc0 + acc1;
    red[lane * NSUB + sub] = accs.x + accs.y;
    __syncthreads();

    if (tid < BTILE) {
        float s = b3[0];
        #pragma unroll
        for (int k = 0; k < NSUB; ++k) s += red[tid * NSUB + k];
        out[b0 + tid] = s;
    }
}

extern "C" void kernel_launch(void* const* d_in, const int* in_sizes, int n_in,
                              void* d_out, int out_size, void* d_ws, size_t ws_size,
                              hipStream_t stream) {
    const float* y  = (const float*)d_in[0];
    const float* W1 = (const float*)d_in[1];
    const float* b1 = (const float*)d_in[2];
    const float* W2 = (const float*)d_in[3];
    const float* b2 = (const float*)d_in[4];
    const float* W3 = (const float*)d_in[5];
    const float* b3 = (const float*)d_in[6];
    float* out = (float*)d_out;

    float* rec = (float*)d_ws;   // 200 * 216 floats = 172.8 KB of ws

    precompute_kernel<<<NF, 256, 0, stream>>>(W1, b1, W2, b2, W3, rec);
    mlp_kernel<<<B_TOTAL / BTILE, BTILE * NSUB, 0, stream>>>(y, rec, b3, out);
}